// Round 1
// baseline (3304.453 us; speedup 1.0000x reference)
//
#include <hip/hip_runtime.h>
#include <stdint.h>

typedef unsigned short u16;
typedef __attribute__((ext_vector_type(8))) short short8;
typedef __attribute__((ext_vector_type(4))) float f32x4;
typedef __attribute__((ext_vector_type(4))) unsigned short u16x4;

__device__ __forceinline__ u16 f2bf(float f) {
  union { float f; uint32_t u; } v; v.f = f;
  uint32_t r = v.u + 0x7FFFu + ((v.u >> 16) & 1u);
  return (u16)(r >> 16);
}
__device__ __forceinline__ float bf2f(u16 u) {
  union { uint32_t u; float f; } v; v.u = ((uint32_t)u) << 16; return v.f;
}
__device__ __forceinline__ float hsig(float x) {
  return fminf(1.0f, fmaxf(0.0f, fmaf(x, 0.2f, 0.5f)));
}
__device__ __forceinline__ float ftanh(float x) {
  float e = __expf(2.0f * x);
  return fmaf(-2.0f, __builtin_amdgcn_rcpf(e + 1.0f), 1.0f);
}

// ---------------- weight transpose+cast: dst[n*dstride + coff + k] = src[k*N + n]
__global__ void k_transpose_cast(const float* __restrict__ src, u16* __restrict__ dst,
                                 int K, int N, int dstride, int coff) {
  int idx = blockIdx.x * blockDim.x + threadIdx.x;
  if (idx >= K * N) return;
  int k = idx / N, n = idx - k * N;
  dst[(size_t)n * dstride + coff + k] = f2bf(src[idx]);
}

// ---------------- fp32 -> bf16 cast with row restride (rows of 512 floats)
__global__ void k_cast_bf16(const float* __restrict__ src, u16* __restrict__ dst,
                            int n4, int dstride, int coff) {
  int i4 = blockIdx.x * blockDim.x + threadIdx.x;
  if (i4 >= n4) return;
  size_t idx = (size_t)i4 * 4;
  f32x4 v = *(const f32x4*)&src[idx];
  size_t r = idx >> 9;
  int c = (int)(idx & 511);
  u16x4 o;
  o[0] = f2bf(v[0]); o[1] = f2bf(v[1]); o[2] = f2bf(v[2]); o[3] = f2bf(v[3]);
  *(u16x4*)&dst[r * dstride + coff + c] = o;
}

// ---------------- bf16 GEMM, C[m][n] = sum_k A[m][k]*Bt[n][k] + bias[n]
// m97 recipe: 128x128 tile, BK=32, 4 waves 2x2, 4x4 16x16x32 MFMAs, global_load_lds w16
template <int OUT_BF16>
__global__ __launch_bounds__(256, 2) void k_gemm(const u16* __restrict__ A,
                                                 const u16* __restrict__ Bt,
                                                 const float* __restrict__ bias,
                                                 void* __restrict__ C,
                                                 int K, int lda, int ldb, int ldc) {
  __shared__ __align__(16) u16 sA[128 * 32];
  __shared__ __align__(16) u16 sB[128 * 32];
  const int tid = threadIdx.x;
  const int wave = tid >> 6, lane = tid & 63;
  const int quad = lane >> 4, l16 = lane & 15;
  const int wm = (wave >> 1) * 64, wn = (wave & 1) * 64;
  const size_t rowA0 = (size_t)blockIdx.x * 128;
  const size_t rowB0 = (size_t)blockIdx.y * 128;

  f32x4 acc[4][4];
#pragma unroll
  for (int i = 0; i < 4; ++i)
#pragma unroll
    for (int j = 0; j < 4; ++j) acc[i][j] = (f32x4){0.f, 0.f, 0.f, 0.f};

  for (int kb = 0; kb < K; kb += 32) {
#pragma unroll
    for (int s = 0; s < 2; ++s) {
      int idx = s * 256 + tid;
      int row = idx >> 2, kc = (idx & 3) * 8;
      const u16* ga = A + (rowA0 + row) * lda + kb + kc;
      const u16* gb = Bt + (rowB0 + row) * ldb + kb + kc;
      u16* la = sA + (size_t)(s * 256 + wave * 64) * 8;
      u16* lb = sB + (size_t)(s * 256 + wave * 64) * 8;
      __builtin_amdgcn_global_load_lds((const __attribute__((address_space(1))) void*)ga,
                                       (__attribute__((address_space(3))) void*)la, 16, 0, 0);
      __builtin_amdgcn_global_load_lds((const __attribute__((address_space(1))) void*)gb,
                                       (__attribute__((address_space(3))) void*)lb, 16, 0, 0);
    }
    __syncthreads();
    short8 af[4], bfr[4];
#pragma unroll
    for (int mi = 0; mi < 4; ++mi)
      af[mi] = *(const short8*)&sA[(wm + mi * 16 + l16) * 32 + quad * 8];
#pragma unroll
    for (int ni = 0; ni < 4; ++ni)
      bfr[ni] = *(const short8*)&sB[(wn + ni * 16 + l16) * 32 + quad * 8];
#pragma unroll
    for (int mi = 0; mi < 4; ++mi)
#pragma unroll
      for (int ni = 0; ni < 4; ++ni)
        acc[mi][ni] =
            __builtin_amdgcn_mfma_f32_16x16x32_bf16(af[mi], bfr[ni], acc[mi][ni], 0, 0, 0);
    __syncthreads();
  }

#pragma unroll
  for (int ni = 0; ni < 4; ++ni) {
    int col = (int)rowB0 + wn + ni * 16 + l16;
    float bv = bias[col];
#pragma unroll
    for (int mi = 0; mi < 4; ++mi) {
      size_t row = rowA0 + wm + mi * 16 + quad * 4;
#pragma unroll
      for (int r = 0; r < 4; ++r) {
        float v = acc[mi][ni][r] + bv;
        if (OUT_BF16)
          ((u16*)C)[(row + r) * ldc + col] = f2bf(v);
        else
          ((float*)C)[(row + r) * ldc + col] = v;
      }
    }
  }
}

// ---------------- bidirectional LSTM recurrence over W=128.
// grid = 32 blocks: block g -> dir = g&1, sequences [ (g>>1)*16, +16 ).
// M=16 (one MFMA m-tile); wave w owns gate-relative n in [w*64, w*64+64).
__global__ __launch_bounds__(256, 1) void k_lstm(const u16* __restrict__ zx_f,
                                                 const u16* __restrict__ zx_b,
                                                 const u16* __restrict__ Uf_t,
                                                 const u16* __restrict__ Ub_t,
                                                 u16* __restrict__ hs) {
  const int g = blockIdx.x;
  const int dir = g & 1;
  const int seq0 = (g >> 1) * 16;
  const u16* zx = dir ? zx_b : zx_f;
  const u16* Ut = dir ? Ub_t : Uf_t;
  const int tid = threadIdx.x;
  const int wave = tid >> 6, lane = tid & 63;
  const int quad = lane >> 4, l16 = lane & 15;

  __shared__ __align__(16) u16 h_lds[16 * 264];   // h[m][k], stride 264 (pad 8)
  __shared__ __align__(16) u16 z_lds[16 * 1040];  // z[m][n], stride 1040 (pad 16)

  for (int i = tid; i < 16 * 264; i += 256) h_lds[i] = 0;

  float c_st[4][4];
#pragma unroll
  for (int q = 0; q < 4; ++q)
#pragma unroll
    for (int r = 0; r < 4; ++r) c_st[q][r] = 0.f;

  {  // stage z(0)
    int tz = dir ? 127 : 0;
#pragma unroll
    for (int s = 0; s < 8; ++s) {
      int idx = s * 256 + tid;
      int row = idx >> 7, col = (idx & 127) * 8;
      *(short8*)&z_lds[row * 1040 + col] =
          *(const short8*)&zx[((size_t)(seq0 + row) * 128 + tz) * 1024 + col];
    }
  }
  __syncthreads();

  for (int t = 0; t < 128; ++t) {
    f32x4 acc[4][4];
#pragma unroll
    for (int G = 0; G < 4; ++G)
#pragma unroll
      for (int q = 0; q < 4; ++q) acc[G][q] = (f32x4){0.f, 0.f, 0.f, 0.f};

#pragma unroll 2
    for (int kk = 0; kk < 8; ++kk) {
      short8 a = *(const short8*)&h_lds[l16 * 264 + kk * 32 + quad * 8];
#pragma unroll
      for (int G = 0; G < 4; ++G)
#pragma unroll
        for (int q = 0; q < 4; ++q) {
          int n = G * 256 + wave * 64 + q * 16 + l16;
          short8 b = *(const short8*)&Ut[(size_t)n * 256 + kk * 32 + quad * 8];
          acc[G][q] = __builtin_amdgcn_mfma_f32_16x16x32_bf16(a, b, acc[G][q], 0, 0, 0);
        }
    }

    const int t_io = dir ? (127 - t) : t;
    float hv[4][4];
#pragma unroll
    for (int q = 0; q < 4; ++q) {
      int nn = wave * 64 + q * 16 + l16;
#pragma unroll
      for (int r = 0; r < 4; ++r) {
        int m = quad * 4 + r;
        float zi = acc[0][q][r] + bf2f(z_lds[m * 1040 + nn]);
        float zf = acc[1][q][r] + bf2f(z_lds[m * 1040 + 256 + nn]);
        float zg = acc[2][q][r] + bf2f(z_lds[m * 1040 + 512 + nn]);
        float zo = acc[3][q][r] + bf2f(z_lds[m * 1040 + 768 + nn]);
        float c = hsig(zf) * c_st[q][r] + hsig(zi) * ftanh(zg);
        float h = hsig(zo) * ftanh(c);
        c_st[q][r] = c;
        hv[q][r] = h;
      }
    }
    __syncthreads();  // all h_lds / z_lds reads of step t complete
#pragma unroll
    for (int q = 0; q < 4; ++q) {
      int nn = wave * 64 + q * 16 + l16;
#pragma unroll
      for (int r = 0; r < 4; ++r) {
        int m = quad * 4 + r;
        u16 hb = f2bf(hv[q][r]);
        h_lds[m * 264 + nn] = hb;
        hs[((size_t)(seq0 + m) * 128 + t_io) * 512 + dir * 256 + nn] = hb;
      }
    }
    if (t < 127) {
      int tz = dir ? (127 - (t + 1)) : (t + 1);
#pragma unroll
      for (int s = 0; s < 8; ++s) {
        int idx = s * 256 + tid;
        int row = idx >> 7, col = (idx & 127) * 8;
        *(short8*)&z_lds[row * 1040 + col] =
            *(const short8*)&zx[((size_t)(seq0 + row) * 128 + tz) * 1024 + col];
      }
    }
    __syncthreads();  // h(t), z(t+1) visible
  }
}

// ---------------- joint LayerNorm over (W,C)=65536 per b; mode 0: out=x+norm (+bf16 copy
// into acat cols 0:512); mode 1: out += norm
__global__ __launch_bounds__(1024) void k_ln(const float* __restrict__ raw,
                                             const float* __restrict__ x,
                                             const float* __restrict__ gamma,
                                             const float* __restrict__ beta,
                                             float* __restrict__ outp,
                                             u16* __restrict__ bfo, int mode) {
  __shared__ float red[32];
  __shared__ float mv[2];
  const int b = blockIdx.x;
  const int tid = threadIdx.x;
  const size_t base = (size_t)b * 65536;
  float s = 0.f, ss = 0.f;
  for (int i = tid * 4; i < 65536; i += 4096) {
    f32x4 v = *(const f32x4*)&raw[base + i];
#pragma unroll
    for (int j = 0; j < 4; ++j) {
      s += v[j];
      ss += v[j] * v[j];
    }
  }
#pragma unroll
  for (int off = 32; off > 0; off >>= 1) {
    s += __shfl_down(s, off);
    ss += __shfl_down(ss, off);
  }
  const int wave = tid >> 6, lane = tid & 63;
  if (lane == 0) {
    red[wave] = s;
    red[16 + wave] = ss;
  }
  __syncthreads();
  if (tid == 0) {
    float S = 0.f, SS = 0.f;
    for (int w = 0; w < 16; ++w) {
      S += red[w];
      SS += red[16 + w];
    }
    float mean = S * (1.f / 65536.f);
    float var = SS * (1.f / 65536.f) - mean * mean;
    mv[0] = mean;
    mv[1] = rsqrtf(var + 1e-3f);
  }
  __syncthreads();
  const float mean = mv[0], rs = mv[1];
  for (int i = tid * 4; i < 65536; i += 4096) {
    f32x4 v = *(const f32x4*)&raw[base + i];
    f32x4 gm = *(const f32x4*)&gamma[i];
    f32x4 bt = *(const f32x4*)&beta[i];
    f32x4 nv;
#pragma unroll
    for (int j = 0; j < 4; ++j) nv[j] = (v[j] - mean) * rs * gm[j] + bt[j];
    if (mode == 0) {
      f32x4 xv = *(const f32x4*)&x[base + i];
      f32x4 res;
#pragma unroll
      for (int j = 0; j < 4; ++j) res[j] = xv[j] + nv[j];
      *(f32x4*)&outp[base + i] = res;
      size_t gi = base + i;
      size_t rrow = gi >> 9;
      int cc = (int)(gi & 511);
      u16x4 o;
      o[0] = f2bf(res[0]); o[1] = f2bf(res[1]); o[2] = f2bf(res[2]); o[3] = f2bf(res[3]);
      *(u16x4*)&bfo[rrow * 1024 + cc] = o;
    } else {
      f32x4 ov = *(const f32x4*)&outp[base + i];
#pragma unroll
      for (int j = 0; j < 4; ++j) ov[j] += nv[j];
      *(f32x4*)&outp[base + i] = ov;
    }
  }
}

// ---------------- inter-LSTM pointwise gates: z[32768,2048] bf16 -> h_new,c_new fp32 + h bf16
__global__ void k_gates(const u16* __restrict__ z, const float* __restrict__ c0,
                        float* __restrict__ hnew, float* __restrict__ cnew,
                        u16* __restrict__ hbf) {
  int i4 = blockIdx.x * blockDim.x + threadIdx.x;
  if (i4 >= 32768 * 128) return;
  size_t idx = (size_t)i4 * 4;
  size_t r = idx >> 9;
  int cix = (int)(idx & 511);
  const u16* zr = z + r * 2048 + cix;
  u16x4 vi = *(const u16x4*)&zr[0];
  u16x4 vf = *(const u16x4*)&zr[512];
  u16x4 vg = *(const u16x4*)&zr[1024];
  u16x4 vo = *(const u16x4*)&zr[1536];
  f32x4 cv = *(const f32x4*)&c0[idx];
  f32x4 ho, co;
  u16x4 hb;
#pragma unroll
  for (int j = 0; j < 4; ++j) {
    float c = hsig(bf2f(vf[j])) * cv[j] + hsig(bf2f(vi[j])) * ftanh(bf2f(vg[j]));
    float h = hsig(bf2f(vo[j])) * ftanh(c);
    co[j] = c;
    ho[j] = h;
    hb[j] = f2bf(h);
  }
  *(f32x4*)&cnew[idx] = co;
  *(f32x4*)&hnew[idx] = ho;
  *(u16x4*)&hbf[idx] = hb;
}

extern "C" void kernel_launch(void* const* d_in, const int* in_sizes, int n_in,
                              void* d_out, int out_size, void* d_ws, size_t ws_size,
                              hipStream_t stream) {
  const float* x    = (const float*)d_in[0];
  const float* h0   = (const float*)d_in[1];
  const float* c0   = (const float*)d_in[2];
  const float* Wf   = (const float*)d_in[3];
  const float* Uf   = (const float*)d_in[4];
  const float* bf   = (const float*)d_in[5];
  const float* Wb   = (const float*)d_in[6];
  const float* Ub   = (const float*)d_in[7];
  const float* bb   = (const float*)d_in[8];
  const float* Wfc1 = (const float*)d_in[9];
  const float* bfc1 = (const float*)d_in[10];
  const float* g1   = (const float*)d_in[11];
  const float* b1   = (const float*)d_in[12];
  const float* Wi   = (const float*)d_in[13];
  const float* Ui   = (const float*)d_in[14];
  const float* bi   = (const float*)d_in[15];
  const float* Wfc2 = (const float*)d_in[16];
  const float* bfc2 = (const float*)d_in[17];
  const float* g2   = (const float*)d_in[18];
  const float* b2   = (const float*)d_in[19];

  char* ws = (char*)d_ws;
  u16* xh   = (u16*)(ws + 0LL);           // 32768x512 bf16 (x); later reused as hs
  u16* hs   = xh;
  u16* zxf  = (u16*)(ws + 33554432LL);    // 32768x1024 bf16
  u16* zxb  = (u16*)(ws + 100663296LL);   // 32768x1024 bf16
  u16* zbuf = zxf;                        // 32768x2048 bf16 (overlays zxf+zxb)
  u16* acat = (u16*)(ws + 167772160LL);   // 32768x1024 bf16: [intra_out | h0]
  float* raw = (float*)(ws + 234881024LL);// 32768x512 fp32 (intra_raw, then inter_raw)
  u16* hnb  = (u16*)(ws + 301989888LL);   // 32768x512 bf16 h_new
  u16* wT   = (u16*)(ws + 335544320LL);   // transposed bf16 weights (8 MB)
  u16* wfT  = wT;                 // [1024,512]
  u16* wbT  = wT + 524288;        // [1024,512]
  u16* ufT  = wT + 1048576;       // [1024,256]
  u16* ubT  = wT + 1310720;       // [1024,256]
  u16* fc1T = wT + 1572864;       // [512,512]
  u16* fc2T = wT + 1835008;       // [512,512]
  u16* catT = wT + 2097152;       // [2048,1024]

  float* out0 = (float*)d_out;
  float* outH = out0 + 16777216;
  float* outC = out0 + 33554432;

  // weight prep (transpose + bf16 cast)
  k_transpose_cast<<<dim3(2048), dim3(256), 0, stream>>>(Wf, wfT, 512, 1024, 512, 0);
  k_transpose_cast<<<dim3(2048), dim3(256), 0, stream>>>(Wb, wbT, 512, 1024, 512, 0);
  k_transpose_cast<<<dim3(1024), dim3(256), 0, stream>>>(Uf, ufT, 256, 1024, 256, 0);
  k_transpose_cast<<<dim3(1024), dim3(256), 0, stream>>>(Ub, ubT, 256, 1024, 256, 0);
  k_transpose_cast<<<dim3(1024), dim3(256), 0, stream>>>(Wfc1, fc1T, 512, 512, 512, 0);
  k_transpose_cast<<<dim3(1024), dim3(256), 0, stream>>>(Wfc2, fc2T, 512, 512, 512, 0);
  k_transpose_cast<<<dim3(4096), dim3(256), 0, stream>>>(Wi, catT, 512, 2048, 1024, 0);
  k_transpose_cast<<<dim3(4096), dim3(256), 0, stream>>>(Ui, catT, 512, 2048, 1024, 512);

  // activation casts
  k_cast_bf16<<<dim3(16384), dim3(256), 0, stream>>>(x, xh, 4194304, 512, 0);
  k_cast_bf16<<<dim3(16384), dim3(256), 0, stream>>>(h0, acat, 4194304, 1024, 512);

  // intra input projections: zx = xi @ W + b  -> bf16 [32768,1024]
  k_gemm<1><<<dim3(256, 8), dim3(256), 0, stream>>>(xh, wfT, bf, (void*)zxf, 512, 512, 512, 1024);
  k_gemm<1><<<dim3(256, 8), dim3(256), 0, stream>>>(xh, wbT, bb, (void*)zxb, 512, 512, 512, 1024);

  // bidirectional recurrence -> hs [32768, 512] (fwd | bwd), overlays xh
  k_lstm<<<dim3(32), dim3(256), 0, stream>>>(zxf, zxb, ufT, ubT, hs);

  // intra dense: raw = hs @ Wfc1 + bfc1 (fp32)
  k_gemm<0><<<dim3(256, 4), dim3(256), 0, stream>>>(hs, fc1T, bfc1, (void*)raw, 512, 512, 512, 512);

  // LN1 + residual: out0 = x + LN(raw); acat[:,0:512] = bf16(out0)
  k_ln<<<dim3(256), dim3(1024), 0, stream>>>(raw, x, g1, b1, out0, acat, 0);

  // inter z = [inter_in | h0] @ [[Wi],[Ui]] + bi -> bf16 [32768, 2048]
  k_gemm<1><<<dim3(256, 16), dim3(256), 0, stream>>>(acat, catT, bi, (void*)zbuf, 1024, 1024, 1024, 2048);

  // gates -> h_new, c_new (fp32 to d_out) + bf16 h_new
  k_gates<<<dim3(16384), dim3(256), 0, stream>>>(zbuf, c0, outH, outC, hnb);

  // inter dense: raw = h_new @ Wfc2 + bfc2 (fp32)
  k_gemm<0><<<dim3(256, 4), dim3(256), 0, stream>>>(hnb, fc2T, bfc2, (void*)raw, 512, 512, 512, 512);

  // LN2 + add into out0
  k_ln<<<dim3(256), dim3(1024), 0, stream>>>(raw, nullptr, g2, b2, out0, nullptr, 1);
}

// Round 2
// 1213.331 us; speedup vs baseline: 2.7235x; 2.7235x over previous
//
#include <hip/hip_runtime.h>
#include <stdint.h>

typedef unsigned short u16;
typedef unsigned char u8;
typedef long long i64;
typedef __attribute__((ext_vector_type(8))) short short8;
typedef __attribute__((ext_vector_type(4))) float f32x4;
typedef __attribute__((ext_vector_type(4))) unsigned short u16x4;

__device__ __forceinline__ u16 f2bf(float f) {
  union { float f; uint32_t u; } v; v.f = f;
  uint32_t r = v.u + 0x7FFFu + ((v.u >> 16) & 1u);
  return (u16)(r >> 16);
}
__device__ __forceinline__ float bf2f(u16 u) {
  union { uint32_t u; float f; } v; v.u = ((uint32_t)u) << 16; return v.f;
}
__device__ __forceinline__ float hsig(float x) {
  return fminf(1.0f, fmaxf(0.0f, fmaf(x, 0.2f, 0.5f)));
}
__device__ __forceinline__ float ftanh(float x) {
  float e = __expf(2.0f * x);
  return fmaf(-2.0f, __builtin_amdgcn_rcpf(e + 1.0f), 1.0f);
}
__device__ __forceinline__ u8 f2fp8(float f) {
  return (u8)(__builtin_amdgcn_cvt_pk_fp8_f32(f, f, 0, false) & 0xff);
}

// ---------------- weight transpose+cast bf16: dst[n*dstride + coff + k] = src[k*N + n]
__global__ void k_transpose_cast(const float* __restrict__ src, u16* __restrict__ dst,
                                 int K, int N, int dstride, int coff) {
  int idx = blockIdx.x * blockDim.x + threadIdx.x;
  if (idx >= K * N) return;
  int k = idx / N, n = idx - k * N;
  dst[(size_t)n * dstride + coff + k] = f2bf(src[idx]);
}

// ---------------- weight transpose+cast fp8: dst[n*K + k] = fp8(src[k*N + n])
__global__ void k_transpose_fp8(const float* __restrict__ src, u8* __restrict__ dst,
                                int K, int N) {
  int idx = blockIdx.x * blockDim.x + threadIdx.x;
  if (idx >= K * N) return;
  int k = idx / N, n = idx - k * N;
  dst[(size_t)n * K + k] = f2fp8(src[idx]);
}

// ---------------- fp32 -> bf16 cast with row restride (rows of 512 floats)
__global__ void k_cast_bf16(const float* __restrict__ src, u16* __restrict__ dst,
                            int n4, int dstride, int coff) {
  int i4 = blockIdx.x * blockDim.x + threadIdx.x;
  if (i4 >= n4) return;
  size_t idx = (size_t)i4 * 4;
  f32x4 v = *(const f32x4*)&src[idx];
  size_t r = idx >> 9;
  int c = (int)(idx & 511);
  u16x4 o;
  o[0] = f2bf(v[0]); o[1] = f2bf(v[1]); o[2] = f2bf(v[2]); o[3] = f2bf(v[3]);
  *(u16x4*)&dst[r * dstride + coff + c] = o;
}

// ---------------- bf16 GEMM, C[m][n] = sum_k A[m][k]*Bt[n][k] + bias[n]
template <int OUT_BF16>
__global__ __launch_bounds__(256, 2) void k_gemm(const u16* __restrict__ A,
                                                 const u16* __restrict__ Bt,
                                                 const float* __restrict__ bias,
                                                 void* __restrict__ C,
                                                 int K, int lda, int ldb, int ldc) {
  __shared__ __align__(16) u16 sA[128 * 32];
  __shared__ __align__(16) u16 sB[128 * 32];
  const int tid = threadIdx.x;
  const int wave = tid >> 6, lane = tid & 63;
  const int quad = lane >> 4, l16 = lane & 15;
  const int wm = (wave >> 1) * 64, wn = (wave & 1) * 64;
  const size_t rowA0 = (size_t)blockIdx.x * 128;
  const size_t rowB0 = (size_t)blockIdx.y * 128;

  f32x4 acc[4][4];
#pragma unroll
  for (int i = 0; i < 4; ++i)
#pragma unroll
    for (int j = 0; j < 4; ++j) acc[i][j] = (f32x4){0.f, 0.f, 0.f, 0.f};

  for (int kb = 0; kb < K; kb += 32) {
#pragma unroll
    for (int s = 0; s < 2; ++s) {
      int idx = s * 256 + tid;
      int row = idx >> 2, kc = (idx & 3) * 8;
      const u16* ga = A + (rowA0 + row) * lda + kb + kc;
      const u16* gb = Bt + (rowB0 + row) * ldb + kb + kc;
      u16* la = sA + (size_t)(s * 256 + wave * 64) * 8;
      u16* lb = sB + (size_t)(s * 256 + wave * 64) * 8;
      __builtin_amdgcn_global_load_lds((const __attribute__((address_space(1))) void*)ga,
                                       (__attribute__((address_space(3))) void*)la, 16, 0, 0);
      __builtin_amdgcn_global_load_lds((const __attribute__((address_space(1))) void*)gb,
                                       (__attribute__((address_space(3))) void*)lb, 16, 0, 0);
    }
    __syncthreads();
    short8 af[4], bfr[4];
#pragma unroll
    for (int mi = 0; mi < 4; ++mi)
      af[mi] = *(const short8*)&sA[(wm + mi * 16 + l16) * 32 + quad * 8];
#pragma unroll
    for (int ni = 0; ni < 4; ++ni)
      bfr[ni] = *(const short8*)&sB[(wn + ni * 16 + l16) * 32 + quad * 8];
#pragma unroll
    for (int mi = 0; mi < 4; ++mi)
#pragma unroll
      for (int ni = 0; ni < 4; ++ni)
        acc[mi][ni] =
            __builtin_amdgcn_mfma_f32_16x16x32_bf16(af[mi], bfr[ni], acc[mi][ni], 0, 0, 0);
    __syncthreads();
  }

#pragma unroll
  for (int ni = 0; ni < 4; ++ni) {
    int col = (int)rowB0 + wn + ni * 16 + l16;
    float bv = bias[col];
#pragma unroll
    for (int mi = 0; mi < 4; ++mi) {
      size_t row = rowA0 + wm + mi * 16 + quad * 4;
#pragma unroll
      for (int r = 0; r < 4; ++r) {
        float v = acc[mi][ni][r] + bv;
        if (OUT_BF16)
          ((u16*)C)[(row + r) * ldc + col] = f2bf(v);
        else
          ((float*)C)[(row + r) * ldc + col] = v;
      }
    }
  }
}

// ---------------- bidirectional LSTM recurrence over W=128, fp8 register-resident U.
// 32 blocks (16 seq-groups x 2 dirs), 512 threads (8 waves), M=16.
// Wave w owns gate-relative cols [w*32, w*32+32) for all 4 gates.
__global__ __launch_bounds__(512, 2) void k_lstm(const u16* __restrict__ zx_f,
                                                 const u16* __restrict__ zx_b,
                                                 const u8* __restrict__ Uf8,
                                                 const u8* __restrict__ Ub8,
                                                 u16* __restrict__ hs) {
  const int g = blockIdx.x;
  const int dir = g & 1;
  const int seq0 = (g >> 1) * 16;
  const u16* zx = dir ? zx_b : zx_f;
  const u8* U8 = dir ? Ub8 : Uf8;
  const int tid = threadIdx.x;
  const int wave = tid >> 6, lane = tid & 63;
  const int quad = lane >> 4, l16 = lane & 15;

  __shared__ __align__(16) u16 z_lds[2][16 * 1032];  // z[m][n], stride 1032 (pad 8)
  __shared__ __align__(8) u8 h_lds[2][16 * 264];     // h fp8 [m][k], stride 264 (pad 8)

  // ---- persistent U fragments: 64 x 8B = 128 VGPRs/lane
  i64 Bf[4][2][8];
#pragma unroll
  for (int G = 0; G < 4; ++G)
#pragma unroll
    for (int q = 0; q < 2; ++q) {
      const u8* base =
          U8 + (size_t)(G * 256 + wave * 32 + q * 16 + l16) * 256 + quad * 8;
#pragma unroll
      for (int kk = 0; kk < 8; ++kk) Bf[G][q][kk] = *(const i64*)(base + kk * 32);
    }

  // zero h buffer 0 (h(0) = 0)
  for (int i = tid; i < (16 * 264) / 4; i += 512) ((uint32_t*)h_lds[0])[i] = 0u;

  // z staging: 4 x short8 = 64 B/thread covers 16x1024 u16
  int zrow[4], zcol[4];
#pragma unroll
  for (int j = 0; j < 4; ++j) {
    int e = tid * 8 + j * 4096;
    zrow[j] = e >> 10;
    zcol[j] = e & 1023;
  }

  short8 zr[4];
  {  // z(0) -> buf0; prefetch z(1) into regs
    int tz = dir ? 127 : 0;
#pragma unroll
    for (int j = 0; j < 4; ++j)
      zr[j] = *(const short8*)&zx[((size_t)(seq0 + zrow[j]) * 128 + tz) * 1024 + zcol[j]];
#pragma unroll
    for (int j = 0; j < 4; ++j) *(short8*)&z_lds[0][zrow[j] * 1032 + zcol[j]] = zr[j];
    tz = dir ? 126 : 1;
#pragma unroll
    for (int j = 0; j < 4; ++j)
      zr[j] = *(const short8*)&zx[((size_t)(seq0 + zrow[j]) * 128 + tz) * 1024 + zcol[j]];
  }
  __syncthreads();

  float c_st[2][4];
#pragma unroll
  for (int q = 0; q < 2; ++q)
#pragma unroll
    for (int r = 0; r < 4; ++r) c_st[q][r] = 0.f;

  for (int t = 0; t < 128; ++t) {
    const int p = t & 1;
    f32x4 acc[4][2];
#pragma unroll
    for (int G = 0; G < 4; ++G)
#pragma unroll
      for (int q = 0; q < 2; ++q) acc[G][q] = (f32x4){0.f, 0.f, 0.f, 0.f};

#pragma unroll
    for (int kk = 0; kk < 8; ++kk) {
      i64 a = *(const i64*)&h_lds[p][l16 * 264 + kk * 32 + quad * 8];
#pragma unroll
      for (int G = 0; G < 4; ++G)
#pragma unroll
        for (int q = 0; q < 2; ++q)
          acc[G][q] =
              __builtin_amdgcn_mfma_f32_16x16x32_fp8_fp8(a, Bf[G][q][kk], acc[G][q], 0, 0, 0);
    }

    // stage z(t+1) regs -> buf p^1; prefetch z(t+2) into regs
#pragma unroll
    for (int j = 0; j < 4; ++j) *(short8*)&z_lds[p ^ 1][zrow[j] * 1032 + zcol[j]] = zr[j];
    {
      int tn = t + 2;
      tn = tn > 127 ? 127 : tn;
      int tz = dir ? 127 - tn : tn;
#pragma unroll
      for (int j = 0; j < 4; ++j)
        zr[j] = *(const short8*)&zx[((size_t)(seq0 + zrow[j]) * 128 + tz) * 1024 + zcol[j]];
    }

    const int t_io = dir ? 127 - t : t;
#pragma unroll
    for (int q = 0; q < 2; ++q) {
      int nw = wave * 32 + q * 16 + l16;
#pragma unroll
      for (int r = 0; r < 4; ++r) {
        int m = quad * 4 + r;
        float zi = acc[0][q][r] + bf2f(z_lds[p][m * 1032 + nw]);
        float zf = acc[1][q][r] + bf2f(z_lds[p][m * 1032 + 256 + nw]);
        float zg = acc[2][q][r] + bf2f(z_lds[p][m * 1032 + 512 + nw]);
        float zo = acc[3][q][r] + bf2f(z_lds[p][m * 1032 + 768 + nw]);
        float c = hsig(zf) * c_st[q][r] + hsig(zi) * ftanh(zg);
        float h = hsig(zo) * ftanh(c);
        c_st[q][r] = c;
        h_lds[p ^ 1][m * 264 + nw] = f2fp8(h);
        hs[((size_t)(seq0 + m) * 128 + t_io) * 512 + dir * 256 + nw] = f2bf(h);
      }
    }
    // barrier WITHOUT vmcnt drain: hs stores + z prefetch stay in flight
    asm volatile("s_waitcnt lgkmcnt(0)\ns_barrier" ::: "memory");
  }
}

// ---------------- joint LayerNorm over (W,C)=65536 per b
__global__ __launch_bounds__(1024) void k_ln(const float* __restrict__ raw,
                                             const float* __restrict__ x,
                                             const float* __restrict__ gamma,
                                             const float* __restrict__ beta,
                                             float* __restrict__ outp,
                                             u16* __restrict__ bfo, int mode) {
  __shared__ float red[32];
  __shared__ float mv[2];
  const int b = blockIdx.x;
  const int tid = threadIdx.x;
  const size_t base = (size_t)b * 65536;
  float s = 0.f, ss = 0.f;
  for (int i = tid * 4; i < 65536; i += 4096) {
    f32x4 v = *(const f32x4*)&raw[base + i];
#pragma unroll
    for (int j = 0; j < 4; ++j) {
      s += v[j];
      ss += v[j] * v[j];
    }
  }
#pragma unroll
  for (int off = 32; off > 0; off >>= 1) {
    s += __shfl_down(s, off);
    ss += __shfl_down(ss, off);
  }
  const int wave = tid >> 6, lane = tid & 63;
  if (lane == 0) {
    red[wave] = s;
    red[16 + wave] = ss;
  }
  __syncthreads();
  if (tid == 0) {
    float S = 0.f, SS = 0.f;
    for (int w = 0; w < 16; ++w) {
      S += red[w];
      SS += red[16 + w];
    }
    float mean = S * (1.f / 65536.f);
    float var = SS * (1.f / 65536.f) - mean * mean;
    mv[0] = mean;
    mv[1] = rsqrtf(var + 1e-3f);
  }
  __syncthreads();
  const float mean = mv[0], rs = mv[1];
  for (int i = tid * 4; i < 65536; i += 4096) {
    f32x4 v = *(const f32x4*)&raw[base + i];
    f32x4 gm = *(const f32x4*)&gamma[i];
    f32x4 bt = *(const f32x4*)&beta[i];
    f32x4 nv;
#pragma unroll
    for (int j = 0; j < 4; ++j) nv[j] = (v[j] - mean) * rs * gm[j] + bt[j];
    if (mode == 0) {
      f32x4 xv = *(const f32x4*)&x[base + i];
      f32x4 res;
#pragma unroll
      for (int j = 0; j < 4; ++j) res[j] = xv[j] + nv[j];
      *(f32x4*)&outp[base + i] = res;
      size_t gi = base + i;
      size_t rrow = gi >> 9;
      int cc = (int)(gi & 511);
      u16x4 o;
      o[0] = f2bf(res[0]); o[1] = f2bf(res[1]); o[2] = f2bf(res[2]); o[3] = f2bf(res[3]);
      *(u16x4*)&bfo[rrow * 1024 + cc] = o;
    } else {
      f32x4 ov = *(const f32x4*)&outp[base + i];
#pragma unroll
      for (int j = 0; j < 4; ++j) ov[j] += nv[j];
      *(f32x4*)&outp[base + i] = ov;
    }
  }
}

// ---------------- inter-LSTM pointwise gates
__global__ void k_gates(const u16* __restrict__ z, const float* __restrict__ c0,
                        float* __restrict__ hnew, float* __restrict__ cnew,
                        u16* __restrict__ hbf) {
  int i4 = blockIdx.x * blockDim.x + threadIdx.x;
  if (i4 >= 32768 * 128) return;
  size_t idx = (size_t)i4 * 4;
  size_t r = idx >> 9;
  int cix = (int)(idx & 511);
  const u16* zr = z + r * 2048 + cix;
  u16x4 vi = *(const u16x4*)&zr[0];
  u16x4 vf = *(const u16x4*)&zr[512];
  u16x4 vg = *(const u16x4*)&zr[1024];
  u16x4 vo = *(const u16x4*)&zr[1536];
  f32x4 cv = *(const f32x4*)&c0[idx];
  f32x4 ho, co;
  u16x4 hb;
#pragma unroll
  for (int j = 0; j < 4; ++j) {
    float c = hsig(bf2f(vf[j])) * cv[j] + hsig(bf2f(vi[j])) * ftanh(bf2f(vg[j]));
    float h = hsig(bf2f(vo[j])) * ftanh(c);
    co[j] = c;
    ho[j] = h;
    hb[j] = f2bf(h);
  }
  *(f32x4*)&cnew[idx] = co;
  *(f32x4*)&hnew[idx] = ho;
  *(u16x4*)&hbf[idx] = hb;
}

extern "C" void kernel_launch(void* const* d_in, const int* in_sizes, int n_in,
                              void* d_out, int out_size, void* d_ws, size_t ws_size,
                              hipStream_t stream) {
  const float* x    = (const float*)d_in[0];
  const float* h0   = (const float*)d_in[1];
  const float* c0   = (const float*)d_in[2];
  const float* Wf   = (const float*)d_in[3];
  const float* Uf   = (const float*)d_in[4];
  const float* bf   = (const float*)d_in[5];
  const float* Wb   = (const float*)d_in[6];
  const float* Ub   = (const float*)d_in[7];
  const float* bb   = (const float*)d_in[8];
  const float* Wfc1 = (const float*)d_in[9];
  const float* bfc1 = (const float*)d_in[10];
  const float* g1   = (const float*)d_in[11];
  const float* b1   = (const float*)d_in[12];
  const float* Wi   = (const float*)d_in[13];
  const float* Ui   = (const float*)d_in[14];
  const float* bi   = (const float*)d_in[15];
  const float* Wfc2 = (const float*)d_in[16];
  const float* bfc2 = (const float*)d_in[17];
  const float* g2   = (const float*)d_in[18];
  const float* b2   = (const float*)d_in[19];

  char* ws = (char*)d_ws;
  u16* xh   = (u16*)(ws + 0LL);           // 32768x512 bf16 (x); later reused as hs
  u16* hs   = xh;
  u16* zxf  = (u16*)(ws + 33554432LL);    // 32768x1024 bf16
  u16* zxb  = (u16*)(ws + 100663296LL);   // 32768x1024 bf16
  u16* zbuf = zxf;                        // 32768x2048 bf16 (overlays zxf+zxb)
  u16* acat = (u16*)(ws + 167772160LL);   // 32768x1024 bf16: [intra_out | h0]
  float* raw = (float*)(ws + 234881024LL);// 32768x512 fp32
  u16* hnb  = (u16*)(ws + 301989888LL);   // 32768x512 bf16 h_new
  u16* wT   = (u16*)(ws + 335544320LL);   // transposed weights (8 MB)
  u16* wfT  = wT;                 // [1024,512] bf16
  u16* wbT  = wT + 524288;        // [1024,512] bf16
  u8*  uf8  = (u8*)(wT + 1048576);  // [1024,256] fp8
  u8*  ub8  = uf8 + 262144;         // [1024,256] fp8
  u16* fc1T = wT + 1572864;       // [512,512] bf16
  u16* fc2T = wT + 1835008;       // [512,512] bf16
  u16* catT = wT + 2097152;       // [2048,1024] bf16

  float* out0 = (float*)d_out;
  float* outH = out0 + 16777216;
  float* outC = out0 + 33554432;

  // weight prep
  k_transpose_cast<<<dim3(2048), dim3(256), 0, stream>>>(Wf, wfT, 512, 1024, 512, 0);
  k_transpose_cast<<<dim3(2048), dim3(256), 0, stream>>>(Wb, wbT, 512, 1024, 512, 0);
  k_transpose_fp8<<<dim3(1024), dim3(256), 0, stream>>>(Uf, uf8, 256, 1024);
  k_transpose_fp8<<<dim3(1024), dim3(256), 0, stream>>>(Ub, ub8, 256, 1024);
  k_transpose_cast<<<dim3(1024), dim3(256), 0, stream>>>(Wfc1, fc1T, 512, 512, 512, 0);
  k_transpose_cast<<<dim3(1024), dim3(256), 0, stream>>>(Wfc2, fc2T, 512, 512, 512, 0);
  k_transpose_cast<<<dim3(4096), dim3(256), 0, stream>>>(Wi, catT, 512, 2048, 1024, 0);
  k_transpose_cast<<<dim3(4096), dim3(256), 0, stream>>>(Ui, catT, 512, 2048, 1024, 512);

  // activation casts
  k_cast_bf16<<<dim3(16384), dim3(256), 0, stream>>>(x, xh, 4194304, 512, 0);
  k_cast_bf16<<<dim3(16384), dim3(256), 0, stream>>>(h0, acat, 4194304, 1024, 512);

  // intra input projections: zx = xi @ W + b -> bf16 [32768,1024]
  k_gemm<1><<<dim3(256, 8), dim3(256), 0, stream>>>(xh, wfT, bf, (void*)zxf, 512, 512, 512, 1024);
  k_gemm<1><<<dim3(256, 8), dim3(256), 0, stream>>>(xh, wbT, bb, (void*)zxb, 512, 512, 512, 1024);

  // bidirectional recurrence -> hs [32768, 512], overlays xh
  k_lstm<<<dim3(32), dim3(512), 0, stream>>>(zxf, zxb, uf8, ub8, hs);

  // intra dense: raw = hs @ Wfc1 + bfc1 (fp32)
  k_gemm<0><<<dim3(256, 4), dim3(256), 0, stream>>>(hs, fc1T, bfc1, (void*)raw, 512, 512, 512, 512);

  // LN1 + residual: out0 = x + LN(raw); acat[:,0:512] = bf16(out0)
  k_ln<<<dim3(256), dim3(1024), 0, stream>>>(raw, x, g1, b1, out0, acat, 0);

  // inter z = [inter_in | h0] @ [[Wi],[Ui]] + bi -> bf16 [32768, 2048]
  k_gemm<1><<<dim3(256, 16), dim3(256), 0, stream>>>(acat, catT, bi, (void*)zbuf, 1024, 1024, 1024, 2048);

  // gates -> h_new, c_new (fp32 to d_out) + bf16 h_new
  k_gates<<<dim3(16384), dim3(256), 0, stream>>>(zbuf, c0, outH, outC, hnb);

  // inter dense: raw = h_new @ Wfc2 + bfc2 (fp32)
  k_gemm<0><<<dim3(256, 4), dim3(256), 0, stream>>>(hnb, fc2T, bfc2, (void*)raw, 512, 512, 512, 512);

  // LN2 + add into out0
  k_ln<<<dim3(256), dim3(1024), 0, stream>>>(raw, nullptr, g2, b2, out0, nullptr, 1);
}